// Round 3
// baseline (10171.295 us; speedup 1.0000x reference)
//
#include <hip/hip_runtime.h>
#include <hip/hip_bf16.h>

// GRU: SEQ=512, B=64, I=512, H=1024, O=512
#define SEQL 512
#define BATCH 64
#define INF 512
#define HID 1024
#define OUTF 512
#define SB (SEQL*BATCH)

typedef __attribute__((ext_vector_type(8))) __bf16 bf16x8;
typedef __attribute__((ext_vector_type(4))) float f32x4;

__device__ inline bf16x8 ld_bf8(const void* p) { return *reinterpret_cast<const bf16x8*>(p); }
__device__ inline unsigned short f2bf(float f) { __bf16 b = (__bf16)f; return __builtin_bit_cast(unsigned short, b); }

// ---------------- prep kernels ----------------
__global__ void cvt_f32_bf16(const float* __restrict__ src, unsigned short* __restrict__ dst, int n) {
    int i = (blockIdx.x * blockDim.x + threadIdx.x) * 4;
    if (i < n) {
        float4 v = *reinterpret_cast<const float4*>(src + i);
        ushort4 o = make_ushort4(f2bf(v.x), f2bf(v.y), f2bf(v.z), f2bf(v.w));
        *reinterpret_cast<ushort4*>(dst + i) = o;
    }
}

__global__ void make_bias2(const float* bxz, const float* bhz, const float* bxr,
                           const float* bhr, float* bias2) {
    int i = blockIdx.x * blockDim.x + threadIdx.x;
    if (i < HID) bias2[i] = bxz[i] + bhz[i];
    else if (i < 2*HID) bias2[i] = bxr[i-HID] + bhr[i-HID];
}

__global__ void fail_sentinel(float* o) { o[0] = 1e9f; }

// ---------------- tiled NT GEMM: C[M,N] = A[M,K] * B[N,K]^T + bias (fp32 out) ----------------
// 128x128 tile, BK=32, 4 waves 2x2, 16x16x32 bf16 MFMA, global_load_lds staging, double-buffered.
// LDS chunk rotation: logical 16B chunk c of row r at slot (c + (r>>1)) & 3 -> 2-way bank alias (free).
__global__ __launch_bounds__(256, 2) void gemm_nt_f32(
        const unsigned short* __restrict__ A, int lda,
        const unsigned short* __restrict__ Bw, int ldb,
        const float* __restrict__ bias,
        float* __restrict__ Cf, int N, int K) {
    __shared__ __align__(16) char lds[32768];
    const int tid = threadIdx.x;
    const int ntn = N >> 7;
    const int bm = blockIdx.x / ntn, bn = blockIdx.x % ntn;
    const int rowbase = bm << 7, colbase = bn << 7;
    const int wave = tid >> 6, lane = tid & 63, lo = lane & 15, hi = lane >> 4;
    const int vm = wave >> 1, vn = wave & 1;

    auto stage = [&](int abase, int k0) {
        #pragma unroll
        for (int i = 0; i < 2; i++) {
            int linear = i * 256 + tid;
            int r = linear >> 2, s = linear & 3;
            int c = (s - (r >> 1)) & 3;
            const unsigned short* ga = A + (size_t)(rowbase + r) * lda + k0 + c * 8;
            const unsigned short* gb = Bw + (size_t)(colbase + r) * ldb + k0 + c * 8;
            __builtin_amdgcn_global_load_lds(
                (const __attribute__((address_space(1))) unsigned int*)ga,
                (__attribute__((address_space(3))) unsigned int*)(lds + abase + linear * 16), 16, 0, 0);
            __builtin_amdgcn_global_load_lds(
                (const __attribute__((address_space(1))) unsigned int*)gb,
                (__attribute__((address_space(3))) unsigned int*)(lds + 16384 + abase + linear * 16), 16, 0, 0);
        }
    };

    f32x4 acc[4][4] = {};
    const int nk = K >> 5;
    stage(0, 0);
    for (int kt = 0; kt < nk; kt++) {
        __syncthreads();                      // staging of current buffer complete
        if (kt + 1 < nk) stage(((kt + 1) & 1) * 8192, (kt + 1) << 5);
        const char* cA = lds + (kt & 1) * 8192;
        const char* cB = lds + 16384 + (kt & 1) * 8192;
        bf16x8 af[4], bfr[4];
        #pragma unroll
        for (int m = 0; m < 4; m++) {
            int r = vm * 64 + m * 16 + lo;
            af[m] = ld_bf8(cA + r * 64 + 16 * ((hi + (r >> 1)) & 3));
        }
        #pragma unroll
        for (int n = 0; n < 4; n++) {
            int r = vn * 64 + n * 16 + lo;
            bfr[n] = ld_bf8(cB + r * 64 + 16 * ((hi + (r >> 1)) & 3));
        }
        #pragma unroll
        for (int m = 0; m < 4; m++)
            #pragma unroll
            for (int n = 0; n < 4; n++)
                acc[m][n] = __builtin_amdgcn_mfma_f32_16x16x32_bf16(af[m], bfr[n], acc[m][n], 0, 0, 0);
        __syncthreads();                      // all reads of current buffer done
    }

    #pragma unroll
    for (int n = 0; n < 4; n++) {
        int col = colbase + vn * 64 + n * 16 + lo;
        float bv = bias[col];
        #pragma unroll
        for (int m = 0; m < 4; m++)
            #pragma unroll
            for (int r = 0; r < 4; r++) {
                int row = rowbase + vm * 64 + m * 16 + hi * 4 + r;
                Cf[(size_t)row * N + col] = acc[m][n][r] + bv;
            }
    }
}

// ---------------- persistent GRU scan (x-projection fused) ----------------
// 128 WGs x 192 threads. wid: rb = wid>>6 (32 batch rows), cb = wid&63 (16 h-cols).
// Wave g in {0=z,1=r,2=hcand} holds [Wh_g | Wx_g] slice (16 cols x (1024+512) bf16) = 192 VGPRs.
// z/r: x-part adds into same preact. hcand: r multiplies ONLY the h-side (h@Whh^T + bhh),
// so wave 2 keeps separate h/x accumulator chains and exchanges both via LDS.
// fp32 hidden state lives in wave 0's registers (MFMA C-layout: row=hi*4+r, col=lo).
__global__ __launch_bounds__(192, 1) void gru_scan(
        const unsigned short* __restrict__ Whc,   // [3][H][H]  (z,r,h)
        const unsigned short* __restrict__ Wxc,   // [3][H][I]  (z,r,h)
        const unsigned short* __restrict__ xbf,   // [S*B][I]
        unsigned short* __restrict__ hs,          // [S+1][B][H]
        const float* __restrict__ bias2,          // [2H]: bxz+bhz | bxr+bhr
        const float* __restrict__ bxh,
        const float* __restrict__ bhh,
        unsigned int* cnt) {
    const int wid = blockIdx.x;
    const int rb = wid >> 6;          // 0..1
    const int cb = wid & 63;          // 0..63
    const int g = threadIdx.x / 64;   // gate/wave
    const int lane = threadIdx.x & 63, lo = lane & 15, hi = lane >> 4;
    const unsigned int nb = gridDim.x;

    __shared__ f32x4 Px[3][2][64];    // [0]=r-pre, [1]=hcand h-part, [2]=hcand x-part

    const int col = cb * 16 + lo;
    // persistent weight fragments
    bf16x8 wh[32], wx[16];
    {
        const unsigned short* p = Whc + ((size_t)g * HID + col) * HID + hi * 8;
        #pragma unroll
        for (int kb = 0; kb < 32; kb++) wh[kb] = ld_bf8(p + kb * 32);
        const unsigned short* q = Wxc + ((size_t)g * HID + col) * INF + hi * 8;
        #pragma unroll
        for (int kb = 0; kb < 16; kb++) wx[kb] = ld_bf8(q + kb * 32);
    }
    const float bzv  = bias2[col];
    const float brv  = bias2[HID + col];
    const float bxhv = bxh[col];
    const float bhhv = bhh[col];
    float hst[2][4] = {};             // fp32 state: row = 32rb+16m+4hi+r, col = 16cb+lo

    for (int t = 0; t < SEQL; t++) {
        const unsigned short* hsrc = hs + (size_t)t * (BATCH * HID);
        const unsigned short* a0p = hsrc + (size_t)(rb * 32 + lo) * HID + hi * 8;
        const unsigned short* x0p = xbf + ((size_t)t * BATCH + rb * 32 + lo) * INF + hi * 8;

        f32x4 ah0 = {0,0,0,0}, ah1 = {0,0,0,0};   // h-side preact
        f32x4 ax0 = {0,0,0,0}, ax1 = {0,0,0,0};   // x-side preact
        #pragma unroll
        for (int kb = 0; kb < 32; kb++) {
            bf16x8 a0 = ld_bf8(a0p + kb * 32);
            bf16x8 a1 = ld_bf8(a0p + 16 * HID + kb * 32);
            ah0 = __builtin_amdgcn_mfma_f32_16x16x32_bf16(a0, wh[kb], ah0, 0, 0, 0);
            ah1 = __builtin_amdgcn_mfma_f32_16x16x32_bf16(a1, wh[kb], ah1, 0, 0, 0);
        }
        #pragma unroll
        for (int kb = 0; kb < 16; kb++) {
            bf16x8 a0 = ld_bf8(x0p + kb * 32);
            bf16x8 a1 = ld_bf8(x0p + 16 * INF + kb * 32);
            ax0 = __builtin_amdgcn_mfma_f32_16x16x32_bf16(a0, wx[kb], ax0, 0, 0, 0);
            ax1 = __builtin_amdgcn_mfma_f32_16x16x32_bf16(a1, wx[kb], ax1, 0, 0, 0);
        }

        if (g == 1) {
            f32x4 v0, v1;
            #pragma unroll
            for (int r = 0; r < 4; r++) { v0[r] = ah0[r] + ax0[r] + brv; v1[r] = ah1[r] + ax1[r] + brv; }
            Px[0][0][lane] = v0; Px[0][1][lane] = v1;
        } else if (g == 2) {
            f32x4 v0, v1, w0, w1;
            #pragma unroll
            for (int r = 0; r < 4; r++) {
                v0[r] = ah0[r] + bhhv; v1[r] = ah1[r] + bhhv;
                w0[r] = ax0[r] + bxhv; w1[r] = ax1[r] + bxhv;
            }
            Px[1][0][lane] = v0; Px[1][1][lane] = v1;
            Px[2][0][lane] = w0; Px[2][1][lane] = w1;
        }
        __syncthreads();

        if (g == 0) {
            unsigned short* hdst = hs + (size_t)(t + 1) * (BATCH * HID);
            f32x4 az[2];
            #pragma unroll
            for (int r = 0; r < 4; r++) { az[0][r] = ah0[r] + ax0[r] + bzv; az[1][r] = ah1[r] + ax1[r] + bzv; }
            f32x4 pr[2] = { Px[0][0][lane], Px[0][1][lane] };
            f32x4 ph[2] = { Px[1][0][lane], Px[1][1][lane] };
            f32x4 px[2] = { Px[2][0][lane], Px[2][1][lane] };
            #pragma unroll
            for (int m = 0; m < 2; m++)
                #pragma unroll
                for (int r = 0; r < 4; r++) {
                    float z  = 1.f / (1.f + __expf(-az[m][r]));
                    float rr = 1.f / (1.f + __expf(-pr[m][r]));
                    float hc = tanhf(px[m][r] + rr * ph[m][r]);
                    hst[m][r] = (1.f - z) * hst[m][r] + z * hc;
                    hdst[(size_t)(rb * 32 + m * 16 + hi * 4 + r) * HID + col] = f2bf(hst[m][r]);
                }
        }

        // --- grid step-barrier: monotonic counter, agent scope ---
        __syncthreads();                       // all waves done (incl. wave0's h-stores issued)
        if (threadIdx.x == 0) {
            __threadfence();                   // make this WG's h-stores device-visible
            __hip_atomic_fetch_add(cnt, 1u, __ATOMIC_ACQ_REL, __HIP_MEMORY_SCOPE_AGENT);
            unsigned int tgt = (unsigned int)(t + 1) * nb;
            while (__hip_atomic_load(cnt, __ATOMIC_ACQUIRE, __HIP_MEMORY_SCOPE_AGENT) < tgt)
                __builtin_amdgcn_s_sleep(2);
        }
        __syncthreads();
    }
}

// ---------------- host ----------------
extern "C" void kernel_launch(void* const* d_in, const int* in_sizes, int n_in,
                              void* d_out, int out_size, void* d_ws, size_t ws_size,
                              hipStream_t stream) {
    const float* x   = (const float*)d_in[0];
    const float* Wxz = (const float*)d_in[1];
    const float* bxz = (const float*)d_in[2];
    const float* Whz = (const float*)d_in[3];
    const float* bhz = (const float*)d_in[4];
    const float* Wxr = (const float*)d_in[5];
    const float* bxr = (const float*)d_in[6];
    const float* Whr = (const float*)d_in[7];
    const float* bhr = (const float*)d_in[8];
    const float* Wxh = (const float*)d_in[9];
    const float* bxh = (const float*)d_in[10];
    const float* Whh = (const float*)d_in[11];
    const float* bhh = (const float*)d_in[12];
    const float* Why = (const float*)d_in[13];
    const float* bhy = (const float*)d_in[14];

    char* ws = (char*)d_ws;
    size_t off = 0;
    auto alloc = [&](size_t bytes) { char* p = ws + off; off += (bytes + 255) & ~(size_t)255; return p; };
    unsigned short* Whc   = (unsigned short*)alloc((size_t)3 * HID * HID * 2);   // 6.3 MB
    unsigned short* Wxc   = (unsigned short*)alloc((size_t)3 * HID * INF * 2);   // 3.1 MB
    unsigned short* Whyb  = (unsigned short*)alloc((size_t)OUTF * HID * 2);      // 1.0 MB
    float*          bias2 = (float*)alloc((size_t)2 * HID * 4);
    unsigned short* hsbuf = (unsigned short*)alloc((size_t)(SEQL + 1) * BATCH * HID * 2); // 67.2 MB
    unsigned int*   cnt   = (unsigned int*)alloc(256);
    // x_bf lives in d_out (dead until K4 overwrites it at the end): 33.5 MB < 67.1 MB
    unsigned short* x_bf  = (unsigned short*)d_out;

    if (off > ws_size) {  // fail LOUD: absmax ~1e9 signature, not a silent zero output
        fail_sentinel<<<dim3(1), dim3(1), 0, stream>>>((float*)d_out);
        return;
    }

    auto cvt = [&](const float* s, unsigned short* d, size_t n) {
        cvt_f32_bf16<<<dim3((unsigned)((n / 4 + 255) / 256)), dim3(256), 0, stream>>>(s, d, (int)n);
    };
    cvt(x, x_bf, (size_t)SB * INF);
    cvt(Whz, Whc, (size_t)HID * HID);
    cvt(Whr, Whc + (size_t)HID * HID, (size_t)HID * HID);
    cvt(Whh, Whc + (size_t)2 * HID * HID, (size_t)HID * HID);
    cvt(Wxz, Wxc, (size_t)HID * INF);
    cvt(Wxr, Wxc + (size_t)HID * INF, (size_t)HID * INF);
    cvt(Wxh, Wxc + (size_t)2 * HID * INF, (size_t)HID * INF);
    cvt(Why, Whyb, (size_t)OUTF * HID);
    make_bias2<<<dim3(8), dim3(256), 0, stream>>>(bxz, bhz, bxr, bhr, bias2);
    (void)hipMemsetAsync(hsbuf, 0, (size_t)BATCH * HID * 2, stream);   // h0 = 0
    (void)hipMemsetAsync(cnt, 0, 256, stream);                         // barrier counter reset

    // scan: 128 WGs on 256 CUs -> trivially co-resident; plain launch (no WG waits on another to finish)
    gru_scan<<<dim3(128), dim3(192), 0, stream>>>(Whc, Wxc, x_bf, hsbuf, bias2, bxh, bhh, cnt);

    // out[SB, O] = hs[1..512] @ Why^T + bhy  (overwrites x_bf region; x_bf is dead here)
    gemm_nt_f32<<<dim3((SB / 128) * (OUTF / 128)), dim3(256), 0, stream>>>(
        hsbuf + (size_t)BATCH * HID, HID, Whyb, HID, bhy, (float*)d_out, OUTF, HID);
}